// Round 1
// baseline (900.411 us; speedup 1.0000x reference)
//
#include <hip/hip_runtime.h>

#define L_NODES 100000
#define NFEAT   256
#define JDIM    128
#define SAMP    8

// ---------------------------------------------------------------------------
// Kernel 1: H = relu(X @ W_h1 + b_h1)      M=L, K=256, N=128
// BM=64, BN=128, BK=32, 256 threads, thread tile 8 rows x 4 cols
// ---------------------------------------------------------------------------
__global__ __launch_bounds__(256) void k_h1(
    const float* __restrict__ X, const float* __restrict__ W,
    const float* __restrict__ b, float* __restrict__ H)
{
    __shared__ float As[32][68];   // [k][m] (stride 68: 16B-aligned, bank-rotated)
    __shared__ float Bs[32][132];  // [k][n]

    const int tid  = threadIdx.x;
    const int row0 = blockIdx.x * 64;
    const int rg = tid >> 5;           // 0..7
    const int cg = tid & 31;           // 0..31
    const int m0 = rg * 8;
    const int n0 = cg * 4;

    float acc[8][4];
    #pragma unroll
    for (int j = 0; j < 8; ++j)
        #pragma unroll
        for (int jj = 0; jj < 4; ++jj) acc[j][jj] = 0.f;

    const int lm = tid >> 3;           // 0..31 (row within half-tile)
    const int lk = (tid & 7) * 4;      // 0..28

    for (int k0 = 0; k0 < NFEAT; k0 += 32) {
        // A tile: 64 rows x 32 k
        #pragma unroll
        for (int h = 0; h < 2; ++h) {
            int m = lm + h * 32;
            int grow = row0 + m;
            float4 v = make_float4(0.f, 0.f, 0.f, 0.f);
            if (grow < L_NODES)
                v = *(const float4*)(X + (size_t)grow * NFEAT + k0 + lk);
            As[lk + 0][m] = v.x; As[lk + 1][m] = v.y;
            As[lk + 2][m] = v.z; As[lk + 3][m] = v.w;
        }
        // B tile: 32 k x 128 n
        {
            const int bk = tid >> 5;
            const int bn = (tid & 31) * 4;
            #pragma unroll
            for (int h = 0; h < 4; ++h) {
                int kk = bk + h * 8;
                float4 v = *(const float4*)(W + (size_t)(k0 + kk) * JDIM + bn);
                *(float4*)&Bs[kk][bn] = v;
            }
        }
        __syncthreads();
        #pragma unroll
        for (int k = 0; k < 32; ++k) {
            float a[8], bb[4];
            *(float4*)&a[0] = *(const float4*)&As[k][m0];
            *(float4*)&a[4] = *(const float4*)&As[k][m0 + 4];
            *(float4*)&bb[0] = *(const float4*)&Bs[k][n0];
            #pragma unroll
            for (int j = 0; j < 8; ++j)
                #pragma unroll
                for (int jj = 0; jj < 4; ++jj)
                    acc[j][jj] = fmaf(a[j], bb[jj], acc[j][jj]);
        }
        __syncthreads();
    }

    float bias[4];
    *(float4*)&bias[0] = *(const float4*)(b + n0);
    #pragma unroll
    for (int j = 0; j < 8; ++j) {
        int grow = row0 + m0 + j;
        if (grow < L_NODES) {
            float4 v;
            v.x = fmaxf(acc[j][0] + bias[0], 0.f);
            v.y = fmaxf(acc[j][1] + bias[1], 0.f);
            v.z = fmaxf(acc[j][2] + bias[2], 0.f);
            v.w = fmaxf(acc[j][3] + bias[3], 0.f);
            *(float4*)(H + (size_t)grow * JDIM + n0) = v;
        }
    }
}

// ---------------------------------------------------------------------------
// Kernel 2: E1[i] = relu( mean_s relu( concat(H[idx0[s,i]],H[idx1[s,i]]) @ W_g1 + b ) )
// Block: 16 nodes x 8 samples = 128 gathered rows x 128 cols, K=256, BK=32.
// Rows ordered r = il*8 + s so each thread's 8 rows are one node's 8 samples
// -> relu+mean reduction happens in registers.
// ---------------------------------------------------------------------------
__global__ __launch_bounds__(256) void k_fk2(
    const float* __restrict__ H, const float* __restrict__ W,
    const float* __restrict__ b,
    const int* __restrict__ idx0, const int* __restrict__ idx1,
    float* __restrict__ E1)
{
    __shared__ float As[32][132];   // [k][row], rows = 128
    __shared__ float Bs[32][132];   // [k][n]
    __shared__ int   sidx[256];     // p*128 + s*16 + il

    const int tid = threadIdx.x;
    const int i0  = blockIdx.x * 16;

    {   // preload all needed indices once
        int p = tid >> 7, rem = tid & 127;
        int s = rem >> 4, il = rem & 15;
        const int* idxp = p ? idx1 : idx0;
        sidx[tid] = idxp[(size_t)s * L_NODES + i0 + il];
    }
    __syncthreads();

    const int rg = tid >> 4;        // 0..15  = node-local index
    const int cg = tid & 15;        // 0..15
    const int n0 = cg * 8;
    const int r0 = rg * 8;

    float acc[8][8];
    #pragma unroll
    for (int j = 0; j < 8; ++j)
        #pragma unroll
        for (int jj = 0; jj < 8; ++jj) acc[j][jj] = 0.f;

    const int lr = tid >> 1;            // row 0..127
    const int lh = (tid & 1) * 16;      // 0 or 16
    const int il = lr >> 3, ls = lr & 7;

    for (int k0 = 0; k0 < 2 * JDIM; k0 += 32) {
        const int p  = k0 >> 7;         // which half of the concat
        const int kb = k0 & 127;        // column base within that H row
        // A tile: 128 gathered rows x 32 k (each thread: 16 floats of one row)
        {
            int src = sidx[p * 128 + ls * 16 + il];
            const float* hp = H + (size_t)src * JDIM + kb + lh;
            #pragma unroll
            for (int w = 0; w < 4; ++w) {
                float4 v = *(const float4*)(hp + w * 4);
                As[lh + w * 4 + 0][lr] = v.x;
                As[lh + w * 4 + 1][lr] = v.y;
                As[lh + w * 4 + 2][lr] = v.z;
                As[lh + w * 4 + 3][lr] = v.w;
            }
        }
        // B tile: W_g1 chunk 32 x 128
        {
            const int bk = tid >> 5;
            const int bn = (tid & 31) * 4;
            #pragma unroll
            for (int h = 0; h < 4; ++h) {
                int kk = bk + h * 8;
                float4 v = *(const float4*)(W + (size_t)(k0 + kk) * JDIM + bn);
                *(float4*)&Bs[kk][bn] = v;
            }
        }
        __syncthreads();
        #pragma unroll
        for (int k = 0; k < 32; ++k) {
            float a[8], bb[8];
            *(float4*)&a[0]  = *(const float4*)&As[k][r0];
            *(float4*)&a[4]  = *(const float4*)&As[k][r0 + 4];
            *(float4*)&bb[0] = *(const float4*)&Bs[k][n0];
            *(float4*)&bb[4] = *(const float4*)&Bs[k][n0 + 4];
            #pragma unroll
            for (int j = 0; j < 8; ++j)
                #pragma unroll
                for (int jj = 0; jj < 8; ++jj)
                    acc[j][jj] = fmaf(a[j], bb[jj], acc[j][jj]);
        }
        __syncthreads();
    }

    // bias + relu, mean over the 8 samples (j dim), relu(mean) (no-op, kept)
    float bias[8];
    *(float4*)&bias[0] = *(const float4*)(b + n0);
    *(float4*)&bias[4] = *(const float4*)(b + n0 + 4);
    float outv[8];
    #pragma unroll
    for (int jj = 0; jj < 8; ++jj) {
        float sum = 0.f;
        #pragma unroll
        for (int j = 0; j < 8; ++j)
            sum += fmaxf(acc[j][jj] + bias[jj], 0.f);
        outv[jj] = fmaxf(sum * 0.125f, 0.f);
    }
    float* dst = E1 + (size_t)(i0 + rg) * JDIM + n0;
    *(float4*)(dst)     = *(float4*)&outv[0];
    *(float4*)(dst + 4) = *(float4*)&outv[4];
}

// ---------------------------------------------------------------------------
// Kernel 3: E2 = relu(concat(H, E1) @ W_g1 + b_g1);  out = E2 @ W_f + b_f
// Same tiling as k1; epilogue routes E2 through LDS for the J->2 head.
// ---------------------------------------------------------------------------
__global__ __launch_bounds__(256) void k_final(
    const float* __restrict__ H, const float* __restrict__ E1,
    const float* __restrict__ Wg, const float* __restrict__ bg,
    const float* __restrict__ Wf, const float* __restrict__ bf,
    float* __restrict__ out)
{
    __shared__ float As[32][68];
    __shared__ float Bs[32][132];
    __shared__ float E2s[64][133];   // stride 133: conflict-free column reads

    const int tid  = threadIdx.x;
    const int row0 = blockIdx.x * 64;
    const int rg = tid >> 5;
    const int cg = tid & 31;
    const int m0 = rg * 8;
    const int n0 = cg * 4;

    float acc[8][4];
    #pragma unroll
    for (int j = 0; j < 8; ++j)
        #pragma unroll
        for (int jj = 0; jj < 4; ++jj) acc[j][jj] = 0.f;

    const int lm = tid >> 3;
    const int lk = (tid & 7) * 4;

    for (int k0 = 0; k0 < 2 * JDIM; k0 += 32) {
        const float* srcmat = (k0 < JDIM) ? H : E1;
        const int kb = k0 & 127;
        #pragma unroll
        for (int h = 0; h < 2; ++h) {
            int m = lm + h * 32;
            int grow = row0 + m;
            float4 v = make_float4(0.f, 0.f, 0.f, 0.f);
            if (grow < L_NODES)
                v = *(const float4*)(srcmat + (size_t)grow * JDIM + kb + lk);
            As[lk + 0][m] = v.x; As[lk + 1][m] = v.y;
            As[lk + 2][m] = v.z; As[lk + 3][m] = v.w;
        }
        {
            const int bk = tid >> 5;
            const int bn = (tid & 31) * 4;
            #pragma unroll
            for (int h = 0; h < 4; ++h) {
                int kk = bk + h * 8;
                float4 v = *(const float4*)(Wg + (size_t)(k0 + kk) * JDIM + bn);
                *(float4*)&Bs[kk][bn] = v;
            }
        }
        __syncthreads();
        #pragma unroll
        for (int k = 0; k < 32; ++k) {
            float a[8], bb[4];
            *(float4*)&a[0] = *(const float4*)&As[k][m0];
            *(float4*)&a[4] = *(const float4*)&As[k][m0 + 4];
            *(float4*)&bb[0] = *(const float4*)&Bs[k][n0];
            #pragma unroll
            for (int j = 0; j < 8; ++j)
                #pragma unroll
                for (int jj = 0; jj < 4; ++jj)
                    acc[j][jj] = fmaf(a[j], bb[jj], acc[j][jj]);
        }
        __syncthreads();
    }

    float bias[4];
    *(float4*)&bias[0] = *(const float4*)(bg + n0);
    #pragma unroll
    for (int j = 0; j < 8; ++j)
        #pragma unroll
        for (int jj = 0; jj < 4; ++jj)
            E2s[m0 + j][n0 + jj] = fmaxf(acc[j][jj] + bias[jj], 0.f);
    __syncthreads();

    if (tid < 128) {
        int n = tid >> 1, o = tid & 1;
        int grow = row0 + n;
        if (grow < L_NODES) {
            float a = bf[o];
            #pragma unroll 8
            for (int k = 0; k < JDIM; ++k)
                a = fmaf(E2s[n][k], Wf[k * 2 + o], a);
            out[(size_t)grow * 2 + o] = a;
        }
    }
}

// ---------------------------------------------------------------------------
extern "C" void kernel_launch(void* const* d_in, const int* in_sizes, int n_in,
                              void* d_out, int out_size, void* d_ws, size_t ws_size,
                              hipStream_t stream) {
    const float* X    = (const float*)d_in[0];
    const float* W_h1 = (const float*)d_in[1];
    const float* b_h1 = (const float*)d_in[2];
    const float* W_g1 = (const float*)d_in[3];
    const float* b_g1 = (const float*)d_in[4];
    const float* W_f  = (const float*)d_in[5];
    const float* b_f  = (const float*)d_in[6];
    const int*   idx0 = (const int*)d_in[7];
    const int*   idx1 = (const int*)d_in[8];
    float* out = (float*)d_out;

    float* H  = (float*)d_ws;                       // L x 128 fp32 = 51.2 MB
    float* E1 = H + (size_t)L_NODES * JDIM;         // L x 128 fp32 = 51.2 MB

    k_h1<<<(L_NODES + 63) / 64, 256, 0, stream>>>(X, W_h1, b_h1, H);
    k_fk2<<<L_NODES / 16, 256, 0, stream>>>(H, W_g1, b_g1, idx0, idx1, E1);
    k_final<<<(L_NODES + 63) / 64, 256, 0, stream>>>(H, E1, W_g1, b_g1, W_f, b_f, out);
}

// Round 2
// 513.533 us; speedup vs baseline: 1.7534x; 1.7534x over previous
//
#include <hip/hip_runtime.h>

#define L_NODES 100000
#define NFEAT   256
#define JDIM    128
#define SAMP    8

typedef __bf16 bf16x8 __attribute__((ext_vector_type(8)));
typedef __bf16 bf16x4 __attribute__((ext_vector_type(4)));
typedef float  floatx4 __attribute__((ext_vector_type(4)));

// ---------------------------------------------------------------------------
// Prep: Wt[n][k] = (bf16) W_g1[k][n]   (128 x 256, 64 KB — L2-resident)
// ---------------------------------------------------------------------------
__global__ __launch_bounds__(256) void k_prep_wt(
    const float* __restrict__ W, __bf16* __restrict__ Wt)
{
    int i = blockIdx.x * 256 + threadIdx.x;     // 32768 elements
    int n = i >> 8, k = i & 255;
    Wt[n * 256 + k] = (__bf16)W[k * JDIM + n];
}

// ---------------------------------------------------------------------------
// Kernel 1: Hb = bf16( relu(X @ W_h1 + b_h1) )   M=L, K=256, N=128  (fp32 math)
// ---------------------------------------------------------------------------
__global__ __launch_bounds__(256) void k_h1(
    const float* __restrict__ X, const float* __restrict__ W,
    const float* __restrict__ b, __bf16* __restrict__ Hb)
{
    __shared__ float As[32][68];
    __shared__ float Bs[32][132];

    const int tid  = threadIdx.x;
    const int row0 = blockIdx.x * 64;
    const int rg = tid >> 5;
    const int cg = tid & 31;
    const int m0 = rg * 8;
    const int n0 = cg * 4;

    float acc[8][4];
    #pragma unroll
    for (int j = 0; j < 8; ++j)
        #pragma unroll
        for (int jj = 0; jj < 4; ++jj) acc[j][jj] = 0.f;

    const int lm = tid >> 3;
    const int lk = (tid & 7) * 4;

    for (int k0 = 0; k0 < NFEAT; k0 += 32) {
        #pragma unroll
        for (int h = 0; h < 2; ++h) {
            int m = lm + h * 32;
            int grow = row0 + m;
            float4 v = make_float4(0.f, 0.f, 0.f, 0.f);
            if (grow < L_NODES)
                v = *(const float4*)(X + (size_t)grow * NFEAT + k0 + lk);
            As[lk + 0][m] = v.x; As[lk + 1][m] = v.y;
            As[lk + 2][m] = v.z; As[lk + 3][m] = v.w;
        }
        {
            const int bk = tid >> 5;
            const int bn = (tid & 31) * 4;
            #pragma unroll
            for (int h = 0; h < 4; ++h) {
                int kk = bk + h * 8;
                float4 v = *(const float4*)(W + (size_t)(k0 + kk) * JDIM + bn);
                *(float4*)&Bs[kk][bn] = v;
            }
        }
        __syncthreads();
        #pragma unroll
        for (int k = 0; k < 32; ++k) {
            float a[8], bb[4];
            *(float4*)&a[0] = *(const float4*)&As[k][m0];
            *(float4*)&a[4] = *(const float4*)&As[k][m0 + 4];
            *(float4*)&bb[0] = *(const float4*)&Bs[k][n0];
            #pragma unroll
            for (int j = 0; j < 8; ++j)
                #pragma unroll
                for (int jj = 0; jj < 4; ++jj)
                    acc[j][jj] = fmaf(a[j], bb[jj], acc[j][jj]);
        }
        __syncthreads();
    }

    float bias[4];
    *(float4*)&bias[0] = *(const float4*)(b + n0);
    #pragma unroll
    for (int j = 0; j < 8; ++j) {
        int grow = row0 + m0 + j;
        if (grow < L_NODES) {
            bf16x4 v;
            v[0] = (__bf16)fmaxf(acc[j][0] + bias[0], 0.f);
            v[1] = (__bf16)fmaxf(acc[j][1] + bias[1], 0.f);
            v[2] = (__bf16)fmaxf(acc[j][2] + bias[2], 0.f);
            v[3] = (__bf16)fmaxf(acc[j][3] + bias[3], 0.f);
            *(bf16x4*)(Hb + (size_t)grow * JDIM + n0) = v;
        }
    }
}

// ---------------------------------------------------------------------------
// Kernel 2 (MFMA): E1b[i] = bf16(relu( mean_s relu( concat(Hb[idx0],Hb[idx1]) @ Wg + b )))
// Block: 16 nodes x 8 samples = 128 rows x 128 cols. Rows sample-major
// (r = s*16 + il) so each 16x16 m-tile is one sample over all 16 nodes and the
// sample-mean is a register add over a wave's 4 m-tiles + one LDS combine.
// A-frags gathered global->VGPR; B-frags from Wt (L2-resident). No K-loop
// barriers, no staging LDS.
// ---------------------------------------------------------------------------
__global__ __launch_bounds__(256) void k_fk2_mfma(
    const __bf16* __restrict__ Hb, const __bf16* __restrict__ Wt,
    const float* __restrict__ b,
    const int* __restrict__ idx0, const int* __restrict__ idx1,
    __bf16* __restrict__ E1b)
{
    __shared__ int   sidx[256];          // [p][s][il]
    __shared__ float red[2][16][132];    // [wr][il][col] (pad 132: 2-way max)

    const int tid = threadIdx.x;
    const int i0  = blockIdx.x * 16;

    {
        int p = tid >> 7, rem = tid & 127;
        int s = rem >> 4, il = rem & 15;
        const int* ip = p ? idx1 : idx0;
        sidx[tid] = ip[(size_t)s * L_NODES + i0 + il];
    }
    __syncthreads();

    const int wave = tid >> 6;
    const int lane = tid & 63;
    const int wr = wave >> 1;        // sample half: samples wr*4..wr*4+3
    const int wc = wave & 1;         // col half:    cols wc*64..wc*64+63
    const int lm = lane & 15;        // A: m(=il) / B: n / C: col
    const int lq = lane >> 4;        // quad: k-group for A/B, row-group for C

    // per-lane A source pointers: [sample-tile][concat-half]
    const __bf16* aptr[4][2];
    #pragma unroll
    for (int t = 0; t < 4; ++t) {
        int s = wr * 4 + t;
        aptr[t][0] = Hb + (size_t)sidx[      s * 16 + lm] * JDIM + lq * 8;
        aptr[t][1] = Hb + (size_t)sidx[128 + s * 16 + lm] * JDIM + lq * 8;
    }
    const __bf16* bptr[4];
    #pragma unroll
    for (int nt = 0; nt < 4; ++nt)
        bptr[nt] = Wt + (size_t)(wc * 64 + nt * 16 + lm) * 256 + lq * 8;

    floatx4 acc[4][4] = {};   // [sample-tile][n-tile]

    #pragma unroll
    for (int ks = 0; ks < 8; ++ks) {         // K = 256, 32 per step
        const int p  = ks >> 2;              // concat half
        const int kb = (ks & 3) * 32;        // offset within half
        bf16x8 af[4], bg[4];
        #pragma unroll
        for (int t = 0; t < 4; ++t)
            af[t] = *(const bf16x8*)(aptr[t][p] + kb);
        #pragma unroll
        for (int nt = 0; nt < 4; ++nt)
            bg[nt] = *(const bf16x8*)(bptr[nt] + ks * 32);
        #pragma unroll
        for (int t = 0; t < 4; ++t)
            #pragma unroll
            for (int nt = 0; nt < 4; ++nt)
                acc[t][nt] = __builtin_amdgcn_mfma_f32_16x16x32_bf16(
                    af[t], bg[nt], acc[t][nt], 0, 0, 0);
    }

    // bias + relu per sample, sum the wave's 4 samples in registers
    #pragma unroll
    for (int nt = 0; nt < 4; ++nt) {
        const int col = wc * 64 + nt * 16 + lm;
        const float bias = b[col];
        floatx4 r = {};
        #pragma unroll
        for (int t = 0; t < 4; ++t)
            #pragma unroll
            for (int p = 0; p < 4; ++p)
                r[p] += fmaxf(acc[t][nt][p] + bias, 0.f);
        #pragma unroll
        for (int p = 0; p < 4; ++p)
            red[wr][lq * 4 + p][col] = r[p];   // C row = lq*4+p = il
    }
    __syncthreads();

    // combine the two sample-halves, mean, relu, store bf16
    {
        int il = tid >> 4, c0 = (tid & 15) * 8;
        bf16x8 o;
        #pragma unroll
        for (int c = 0; c < 8; ++c)
            o[c] = (__bf16)fmaxf((red[0][il][c0 + c] + red[1][il][c0 + c]) * 0.125f, 0.f);
        *(bf16x8*)(E1b + (size_t)(i0 + il) * JDIM + c0) = o;
    }
}

// ---------------------------------------------------------------------------
// Kernel 3: E2 = relu(concat(Hb, E1b) @ W_g1 + b_g1);  out = E2 @ W_f + b_f
// fp32 math, bf16 A-staging (converted into LDS).
// ---------------------------------------------------------------------------
__global__ __launch_bounds__(256) void k_final(
    const __bf16* __restrict__ Hb, const __bf16* __restrict__ E1b,
    const float* __restrict__ Wg, const float* __restrict__ bg,
    const float* __restrict__ Wf, const float* __restrict__ bf,
    float* __restrict__ out)
{
    __shared__ float As[32][68];
    __shared__ float Bs[32][132];
    __shared__ float E2s[64][133];

    const int tid  = threadIdx.x;
    const int row0 = blockIdx.x * 64;
    const int rg = tid >> 5;
    const int cg = tid & 31;
    const int m0 = rg * 8;
    const int n0 = cg * 4;

    float acc[8][4];
    #pragma unroll
    for (int j = 0; j < 8; ++j)
        #pragma unroll
        for (int jj = 0; jj < 4; ++jj) acc[j][jj] = 0.f;

    const int lm = tid >> 2;          // 0..63 row
    const int lk = (tid & 3) * 8;     // 0,8,16,24

    for (int k0 = 0; k0 < 2 * JDIM; k0 += 32) {
        const __bf16* srcmat = (k0 < JDIM) ? Hb : E1b;
        const int kb = k0 & 127;
        {
            int grow = row0 + lm;
            bf16x8 v = {};
            if (grow < L_NODES)
                v = *(const bf16x8*)(srcmat + (size_t)grow * JDIM + kb + lk);
            #pragma unroll
            for (int j = 0; j < 8; ++j) As[lk + j][lm] = (float)v[j];
        }
        {
            const int bk = tid >> 5;
            const int bn = (tid & 31) * 4;
            #pragma unroll
            for (int h = 0; h < 4; ++h) {
                int kk = bk + h * 8;
                float4 v = *(const float4*)(Wg + (size_t)(k0 + kk) * JDIM + bn);
                *(float4*)&Bs[kk][bn] = v;
            }
        }
        __syncthreads();
        #pragma unroll
        for (int k = 0; k < 32; ++k) {
            float a[8], bb[4];
            *(float4*)&a[0] = *(const float4*)&As[k][m0];
            *(float4*)&a[4] = *(const float4*)&As[k][m0 + 4];
            *(float4*)&bb[0] = *(const float4*)&Bs[k][n0];
            #pragma unroll
            for (int j = 0; j < 8; ++j)
                #pragma unroll
                for (int jj = 0; jj < 4; ++jj)
                    acc[j][jj] = fmaf(a[j], bb[jj], acc[j][jj]);
        }
        __syncthreads();
    }

    float bias[4];
    *(float4*)&bias[0] = *(const float4*)(bg + n0);
    #pragma unroll
    for (int j = 0; j < 8; ++j)
        #pragma unroll
        for (int jj = 0; jj < 4; ++jj)
            E2s[m0 + j][n0 + jj] = fmaxf(acc[j][jj] + bias[jj], 0.f);
    __syncthreads();

    if (tid < 128) {
        int n = tid >> 1, o = tid & 1;
        int grow = row0 + n;
        if (grow < L_NODES) {
            float a = bf[o];
            #pragma unroll 8
            for (int k = 0; k < JDIM; ++k)
                a = fmaf(E2s[n][k], Wf[k * 2 + o], a);
            out[(size_t)grow * 2 + o] = a;
        }
    }
}

// ---------------------------------------------------------------------------
extern "C" void kernel_launch(void* const* d_in, const int* in_sizes, int n_in,
                              void* d_out, int out_size, void* d_ws, size_t ws_size,
                              hipStream_t stream) {
    const float* X    = (const float*)d_in[0];
    const float* W_h1 = (const float*)d_in[1];
    const float* b_h1 = (const float*)d_in[2];
    const float* W_g1 = (const float*)d_in[3];
    const float* b_g1 = (const float*)d_in[4];
    const float* W_f  = (const float*)d_in[5];
    const float* b_f  = (const float*)d_in[6];
    const int*   idx0 = (const int*)d_in[7];
    const int*   idx1 = (const int*)d_in[8];
    float* out = (float*)d_out;

    __bf16* Hb  = (__bf16*)d_ws;                          // L x 128 bf16 = 25.6 MB
    __bf16* E1b = Hb + (size_t)L_NODES * JDIM;            // L x 128 bf16 = 25.6 MB
    __bf16* Wt  = E1b + (size_t)L_NODES * JDIM;           // 128 x 256 bf16 = 64 KB

    k_prep_wt<<<128, 256, 0, stream>>>(W_g1, Wt);
    k_h1<<<(L_NODES + 63) / 64, 256, 0, stream>>>(X, W_h1, b_h1, Hb);
    k_fk2_mfma<<<L_NODES / 16, 256, 0, stream>>>(Hb, Wt, b_g1, idx0, idx1, E1b);
    k_final<<<(L_NODES + 63) / 64, 256, 0, stream>>>(Hb, E1b, W_g1, b_g1, W_f, b_f, out);
}

// Round 3
// 409.537 us; speedup vs baseline: 2.1986x; 1.2539x over previous
//
#include <hip/hip_runtime.h>

#define L_NODES 100000
#define NFEAT   256
#define JDIM    128

typedef __bf16 bf16x8 __attribute__((ext_vector_type(8)));
typedef __bf16 bf16x4 __attribute__((ext_vector_type(4)));
typedef float  floatx4 __attribute__((ext_vector_type(4)));

// ---------------------------------------------------------------------------
// Prep: WtH[n][k] = bf16(W_h1[k][n]), WtG[n][k] = bf16(W_g1[k][n])  (64 KB each)
// ---------------------------------------------------------------------------
__global__ __launch_bounds__(256) void k_prep(
    const float* __restrict__ Wh, const float* __restrict__ Wg,
    __bf16* __restrict__ WtH, __bf16* __restrict__ WtG)
{
    int i = blockIdx.x * 256 + threadIdx.x;   // 32768
    int n = i >> 8, k = i & 255;
    WtH[i] = (__bf16)Wh[k * JDIM + n];
    WtG[i] = (__bf16)Wg[k * JDIM + n];
}

// ---------------------------------------------------------------------------
// Kernel 1 (MFMA): Hb = bf16(relu(X @ W_h1 + b))   M=L K=256 N=128
// Block 128x128, 4 waves = (mh, wc), wave = 4 m-tiles x 4 n-tiles.
// A staged fp32->bf16 through LDS in two K-halves (34.8 KB).
// ---------------------------------------------------------------------------
__global__ __launch_bounds__(256) void k_h1_mfma(
    const float* __restrict__ X, const __bf16* __restrict__ WtH,
    const float* __restrict__ b, __bf16* __restrict__ Hb)
{
    __shared__ __bf16 As[128][136];   // stride 136: +4 banks/row, 2-way max

    const int tid  = threadIdx.x;
    const int row0 = blockIdx.x * 128;
    const int wave = tid >> 6, lane = tid & 63;
    const int mh = wave >> 1, wc = wave & 1;
    const int lm = lane & 15, lq = lane >> 4;

    const __bf16* bptr[4];
    #pragma unroll
    for (int nt = 0; nt < 4; ++nt)
        bptr[nt] = WtH + (size_t)(wc * 64 + nt * 16 + lm) * 256 + lq * 8;

    floatx4 acc[4][4] = {};
    bf16x8 bc[4], bn[4];
    #pragma unroll
    for (int nt = 0; nt < 4; ++nt) bc[nt] = *(const bf16x8*)bptr[nt];

    for (int half = 0; half < 2; ++half) {
        // stage 128 rows x 128 k fp32 -> bf16 LDS (fully coalesced)
        #pragma unroll
        for (int it = 0; it < 16; ++it) {
            int f4  = it * 256 + tid;          // float4 index in 128x128 tile
            int row = f4 >> 5;                 // 32 float4 per row
            int c4  = f4 & 31;
            int grow = row0 + row; if (grow >= L_NODES) grow = L_NODES - 1;
            float4 v = *(const float4*)(X + (size_t)grow * NFEAT + half * 128 + c4 * 4);
            bf16x4 o; o[0]=(__bf16)v.x; o[1]=(__bf16)v.y; o[2]=(__bf16)v.z; o[3]=(__bf16)v.w;
            *(bf16x4*)&As[row][c4 * 4] = o;
        }
        __syncthreads();
        #pragma unroll
        for (int ksl = 0; ksl < 4; ++ksl) {
            int ks = half * 4 + ksl;
            if (ks < 7)
                #pragma unroll
                for (int nt = 0; nt < 4; ++nt)
                    bn[nt] = *(const bf16x8*)(bptr[nt] + (ks + 1) * 32);
            bf16x8 af[4];
            #pragma unroll
            for (int t = 0; t < 4; ++t)
                af[t] = *(const bf16x8*)&As[mh * 64 + t * 16 + lm][ksl * 32 + lq * 8];
            #pragma unroll
            for (int t = 0; t < 4; ++t)
                #pragma unroll
                for (int nt = 0; nt < 4; ++nt)
                    acc[t][nt] = __builtin_amdgcn_mfma_f32_16x16x32_bf16(
                        af[t], bc[nt], acc[t][nt], 0, 0, 0);
            #pragma unroll
            for (int nt = 0; nt < 4; ++nt) bc[nt] = bn[nt];
        }
        __syncthreads();
    }

    // epilogue: bias+relu -> bf16 into LDS (reuse As), then coalesced store
    #pragma unroll
    for (int nt = 0; nt < 4; ++nt) {
        int col = wc * 64 + nt * 16 + lm;
        float bias = b[col];
        #pragma unroll
        for (int t = 0; t < 4; ++t)
            #pragma unroll
            for (int p = 0; p < 4; ++p)
                As[mh * 64 + t * 16 + lq * 4 + p][col] =
                    (__bf16)fmaxf(acc[t][nt][p] + bias, 0.f);
    }
    __syncthreads();
    {
        int row = tid >> 1, hf = tid & 1;
        int grow = row0 + row;
        if (grow < L_NODES) {
            #pragma unroll
            for (int j = 0; j < 8; ++j) {
                bf16x8 v = *(bf16x8*)&As[row][hf * 64 + j * 8];
                *(bf16x8*)(Hb + (size_t)grow * JDIM + hf * 64 + j * 8) = v;
            }
        }
    }
}

// ---------------------------------------------------------------------------
// Kernel 2 (MFMA): E1b[i] = bf16(relu(mean_s relu(concat(Hb[idx0],Hb[idx1])@Wg + b)))
// 16 nodes x 8 samples per block; wave (wr,wc) = 4 sample-tiles x 4 n-tiles.
// ALL 32 A-gather fragments hoisted to VGPRs up front (one latency exposure
// per block); idx loaded per-lane directly (no LDS, no barrier); B per-ks
// double-buffered from L2-hot WtG.
// ---------------------------------------------------------------------------
__global__ __launch_bounds__(256) void k_fk2_mfma(
    const __bf16* __restrict__ Hb, const __bf16* __restrict__ Wt,
    const float* __restrict__ b,
    const int* __restrict__ idx0, const int* __restrict__ idx1,
    __bf16* __restrict__ E1b)
{
    __shared__ float red[2][16][132];

    const int tid = threadIdx.x;
    const int i0  = blockIdx.x * 16;
    const int wave = tid >> 6, lane = tid & 63;
    const int wr = wave >> 1, wc = wave & 1;
    const int lm = lane & 15, lq = lane >> 4;

    const __bf16* aptr[4][2];
    #pragma unroll
    for (int t = 0; t < 4; ++t) {
        int s = wr * 4 + t;
        int r0i = idx0[(size_t)s * L_NODES + i0 + lm];
        int r1i = idx1[(size_t)s * L_NODES + i0 + lm];
        aptr[t][0] = Hb + (size_t)r0i * JDIM + lq * 8;
        aptr[t][1] = Hb + (size_t)r1i * JDIM + lq * 8;
    }

    // hoist all A fragments: 4 tiles x 8 ks x 16B = 128 VGPRs, 32 loads in flight
    bf16x8 aall[4][8];
    #pragma unroll
    for (int t = 0; t < 4; ++t)
        #pragma unroll
        for (int ks = 0; ks < 8; ++ks)
            aall[t][ks] = *(const bf16x8*)(aptr[t][ks >> 2] + (ks & 3) * 32);

    const __bf16* bptr[4];
    #pragma unroll
    for (int nt = 0; nt < 4; ++nt)
        bptr[nt] = Wt + (size_t)(wc * 64 + nt * 16 + lm) * 256 + lq * 8;

    floatx4 acc[4][4] = {};
    bf16x8 bc[4], bn[4];
    #pragma unroll
    for (int nt = 0; nt < 4; ++nt) bc[nt] = *(const bf16x8*)bptr[nt];

    #pragma unroll
    for (int ks = 0; ks < 8; ++ks) {
        if (ks < 7)
            #pragma unroll
            for (int nt = 0; nt < 4; ++nt)
                bn[nt] = *(const bf16x8*)(bptr[nt] + (ks + 1) * 32);
        #pragma unroll
        for (int t = 0; t < 4; ++t)
            #pragma unroll
            for (int nt = 0; nt < 4; ++nt)
                acc[t][nt] = __builtin_amdgcn_mfma_f32_16x16x32_bf16(
                    aall[t][ks], bc[nt], acc[t][nt], 0, 0, 0);
        #pragma unroll
        for (int nt = 0; nt < 4; ++nt) bc[nt] = bn[nt];
    }

    // bias+relu per sample, register-sum 4 samples, LDS-combine the two halves
    #pragma unroll
    for (int nt = 0; nt < 4; ++nt) {
        const int col = wc * 64 + nt * 16 + lm;
        const float bias = b[col];
        floatx4 r = {};
        #pragma unroll
        for (int t = 0; t < 4; ++t)
            #pragma unroll
            for (int p = 0; p < 4; ++p)
                r[p] += fmaxf(acc[t][nt][p] + bias, 0.f);
        #pragma unroll
        for (int p = 0; p < 4; ++p)
            red[wr][lq * 4 + p][col] = r[p];
    }
    __syncthreads();
    {
        int il = tid >> 4, c0 = (tid & 15) * 8;
        bf16x8 o;
        #pragma unroll
        for (int c = 0; c < 8; ++c)
            o[c] = (__bf16)fmaxf((red[0][il][c0 + c] + red[1][il][c0 + c]) * 0.125f, 0.f);
        *(bf16x8*)(E1b + (size_t)(i0 + il) * JDIM + c0) = o;
    }
}

// ---------------------------------------------------------------------------
// Kernel 3 (MFMA): E2 = relu(concat(Hb,E1b) @ Wg + bg);  out = E2 @ Wf + bf
// Block 128 rows x 128 cols; wave w = 2 m-tiles x 8 n-tiles (no A duplication).
// A (already bf16) loaded direct global->VGPR, all-K hoisted. Head fused via
// bf16 LDS round-trip.
// ---------------------------------------------------------------------------
__global__ __launch_bounds__(256) void k_final_mfma(
    const __bf16* __restrict__ Hb, const __bf16* __restrict__ E1b,
    const __bf16* __restrict__ Wt, const float* __restrict__ bg,
    const float* __restrict__ Wf, const float* __restrict__ bf,
    float* __restrict__ out)
{
    __shared__ __bf16 E2s[128][136];

    const int tid  = threadIdx.x;
    const int row0 = blockIdx.x * 128;
    const int wave = tid >> 6, lane = tid & 63;
    const int lm = lane & 15, lq = lane >> 4;

    // all-K A fragments: 2 m-tiles x 8 ks = 64 VGPRs
    bf16x8 aall[2][8];
    #pragma unroll
    for (int t = 0; t < 2; ++t) {
        int grow = row0 + wave * 32 + t * 16 + lm;
        if (grow >= L_NODES) grow = L_NODES - 1;
        const __bf16* hp = Hb  + (size_t)grow * JDIM + lq * 8;
        const __bf16* ep = E1b + (size_t)grow * JDIM + lq * 8;
        #pragma unroll
        for (int kc = 0; kc < 4; ++kc) {
            aall[t][kc]     = *(const bf16x8*)(hp + kc * 32);
            aall[t][kc + 4] = *(const bf16x8*)(ep + kc * 32);
        }
    }

    const __bf16* bptr[8];
    #pragma unroll
    for (int nt = 0; nt < 8; ++nt)
        bptr[nt] = Wt + (size_t)(nt * 16 + lm) * 256 + lq * 8;

    floatx4 acc[2][8] = {};
    bf16x8 bc[8], bn[8];
    #pragma unroll
    for (int nt = 0; nt < 8; ++nt) bc[nt] = *(const bf16x8*)bptr[nt];

    #pragma unroll
    for (int ks = 0; ks < 8; ++ks) {
        if (ks < 7)
            #pragma unroll
            for (int nt = 0; nt < 8; ++nt)
                bn[nt] = *(const bf16x8*)(bptr[nt] + (ks + 1) * 32);
        #pragma unroll
        for (int t = 0; t < 2; ++t)
            #pragma unroll
            for (int nt = 0; nt < 8; ++nt)
                acc[t][nt] = __builtin_amdgcn_mfma_f32_16x16x32_bf16(
                    aall[t][ks], bc[nt], acc[t][nt], 0, 0, 0);
        #pragma unroll
        for (int nt = 0; nt < 8; ++nt) bc[nt] = bn[nt];
    }

    // E2 -> LDS (bf16)
    #pragma unroll
    for (int nt = 0; nt < 8; ++nt) {
        int col = nt * 16 + lm;
        float bias = bg[col];
        #pragma unroll
        for (int t = 0; t < 2; ++t)
            #pragma unroll
            for (int p = 0; p < 4; ++p)
                E2s[wave * 32 + t * 16 + lq * 4 + p][col] =
                    (__bf16)fmaxf(acc[t][nt][p] + bias, 0.f);
    }
    __syncthreads();

    // head: out[row][o] = E2[row] . Wf[:,o] + bf[o]
    {
        int row = tid >> 1, o = tid & 1;
        int grow = row0 + row;
        if (grow < L_NODES) {
            float a = bf[o];
            #pragma unroll
            for (int j = 0; j < 16; ++j) {
                bf16x8 v = *(bf16x8*)&E2s[row][j * 8];
                #pragma unroll
                for (int c = 0; c < 8; ++c)
                    a = fmaf((float)v[c], Wf[(j * 8 + c) * 2 + o], a);
            }
            out[(size_t)grow * 2 + o] = a;
        }
    }
}

// ---------------------------------------------------------------------------
extern "C" void kernel_launch(void* const* d_in, const int* in_sizes, int n_in,
                              void* d_out, int out_size, void* d_ws, size_t ws_size,
                              hipStream_t stream) {
    const float* X    = (const float*)d_in[0];
    const float* W_h1 = (const float*)d_in[1];
    const float* b_h1 = (const float*)d_in[2];
    const float* W_g1 = (const float*)d_in[3];
    const float* b_g1 = (const float*)d_in[4];
    const float* W_f  = (const float*)d_in[5];
    const float* b_f  = (const float*)d_in[6];
    const int*   idx0 = (const int*)d_in[7];
    const int*   idx1 = (const int*)d_in[8];
    float* out = (float*)d_out;

    __bf16* Hb  = (__bf16*)d_ws;                          // L x 128 bf16 = 25.6 MB
    __bf16* E1b = Hb + (size_t)L_NODES * JDIM;            // L x 128 bf16 = 25.6 MB
    __bf16* WtH = E1b + (size_t)L_NODES * JDIM;           // 128 x 256 bf16 = 64 KB
    __bf16* WtG = WtH + 128 * 256;                        // 128 x 256 bf16 = 64 KB

    k_prep<<<128, 256, 0, stream>>>(W_h1, W_g1, WtH, WtG);
    k_h1_mfma<<<(L_NODES + 127) / 128, 256, 0, stream>>>(X, WtH, b_h1, Hb);
    k_fk2_mfma<<<L_NODES / 16, 256, 0, stream>>>(Hb, WtG, b_g1, idx0, idx1, E1b);
    k_final_mfma<<<(L_NODES + 127) / 128, 256, 0, stream>>>(Hb, E1b, WtG, b_g1, W_f, b_f, out);
}